// Round 1
// baseline (962.566 us; speedup 1.0000x reference)
//
#include <hip/hip_runtime.h>
#include <hip/hip_bf16.h>
#include <stdint.h>

#define IN_F  2048
#define OUT_F 2048
#define BATCH 32768

typedef __attribute__((ext_vector_type(8))) short  short8;   // 8 x bf16 (4 VGPRs)
typedef __attribute__((ext_vector_type(4))) float  floatx4;  // MFMA C/D

// async global->LDS, 16B/lane. LDS dest is wave-uniform base + lane*16.
#define GLD16(g, l) __builtin_amdgcn_global_load_lds( \
    (const __attribute__((address_space(1))) void*)(g), \
    (__attribute__((address_space(3))) void*)(l), 16, 0, 0)

__device__ __forceinline__ uint16_t f2bf(float f) {
  union { float f; uint32_t u; } v; v.f = f;
  uint32_t r = v.u + 0x7FFFu + ((v.u >> 16) & 1u);  // RNE
  return (uint16_t)(r >> 16);
}

// ---------------- K1: P (fp32 [k][i]) -> PT (bf16 [i][k]) ----------------
__global__ __launch_bounds__(256) void k_transpose_bf16(
    const float* __restrict__ P, uint16_t* __restrict__ PT) {
  __shared__ float tile[32][33];
  const int bx = blockIdx.x * 32;  // i
  const int by = blockIdx.y * 32;  // k
  const int tx = threadIdx.x & 31;
  const int ty = threadIdx.x >> 5;  // 0..7
#pragma unroll
  for (int i = 0; i < 32; i += 8)
    tile[ty + i][tx] = P[(size_t)(by + ty + i) * IN_F + bx + tx];
  __syncthreads();
#pragma unroll
  for (int i = 0; i < 32; i += 8)
    PT[(size_t)(bx + ty + i) * IN_F + by + tx] = f2bf(tile[tx][ty + i]);
}

// ------- K2: colsum[j] += sum_i |sum_k PT[i,k] PT[j,k]|  (128x128 tiles) -------
__global__ __launch_bounds__(256) void k_gram_colsum(
    const uint16_t* __restrict__ PT, float* __restrict__ colsum) {
  __shared__ __align__(16) uint16_t lA[128 * 32];
  __shared__ __align__(16) uint16_t lB[128 * 32];
  __shared__ float colpart[128];

  const int tid = threadIdx.x;
  const int wave = tid >> 6, lane = tid & 63;
  const int bm = blockIdx.x * 128, bn = blockIdx.y * 128;
  const int wm = (wave >> 1) * 64, wn = (wave & 1) * 64;

  floatx4 z = {0.f, 0.f, 0.f, 0.f};
  floatx4 acc[4][4];
#pragma unroll
  for (int i = 0; i < 4; i++)
#pragma unroll
    for (int j = 0; j < 4; j++) acc[i][j] = z;

  const int srow = wave * 32 + (lane >> 2);   // staging row (2 chunks/wave)
  const int scol = (lane & 3) * 8;            // ushort offset (16B granules)
  const uint16_t* gA0 = PT + (size_t)(bm + srow) * IN_F + scol;
  const uint16_t* gA1 = gA0 + 16 * IN_F;
  const uint16_t* gB0 = PT + (size_t)(bn + srow) * IN_F + scol;
  const uint16_t* gB1 = gB0 + 16 * IN_F;
  uint16_t* lA0 = &lA[wave * 1024]; uint16_t* lA1 = lA0 + 512;
  uint16_t* lB0 = &lB[wave * 1024]; uint16_t* lB1 = lB0 + 512;

  const int la = (wm + (lane & 15)) * 32 + (lane >> 4) * 8;
  const int lb = (wn + (lane & 15)) * 32 + (lane >> 4) * 8;

  for (int k0 = 0; k0 < IN_F; k0 += 32) {
    GLD16(gA0, lA0); GLD16(gA1, lA1);
    GLD16(gB0, lB0); GLD16(gB1, lB1);
    gA0 += 32; gA1 += 32; gB0 += 32; gB1 += 32;
    __syncthreads();
    short8 af[4], bf[4];
#pragma unroll
    for (int i = 0; i < 4; i++) {
      af[i] = *(const short8*)&lA[la + i * 512];
      bf[i] = *(const short8*)&lB[lb + i * 512];
    }
#pragma unroll
    for (int i = 0; i < 4; i++)
#pragma unroll
      for (int j = 0; j < 4; j++)
        acc[i][j] = __builtin_amdgcn_mfma_f32_16x16x32_bf16(af[i], bf[j], acc[i][j], 0, 0, 0);
    __syncthreads();
  }

  if (tid < 128) colpart[tid] = 0.f;
  __syncthreads();
#pragma unroll
  for (int j = 0; j < 4; j++) {
    float s = 0.f;
#pragma unroll
    for (int i = 0; i < 4; i++)
#pragma unroll
      for (int r = 0; r < 4; r++) s += fabsf(acc[i][j][r]);
    atomicAdd(&colpart[wn + j * 16 + (lane & 15)], s);
  }
  __syncthreads();
  if (tid < 128) atomicAdd(&colsum[bn + tid], colpart[tid]);
}

// ---------------- K3 ----------------
__global__ void k_finalize_d(const float* __restrict__ colsum, float* __restrict__ dv) {
  int i = blockIdx.x * blockDim.x + threadIdx.x;
  if (i < IN_F) dv[i] = 1.0f / sqrtf(colsum[i] + 1e-10f);
}

// ---------------- K4: WB[o,k] = bf16(P[o,k]*d[k]) ----------------
__global__ __launch_bounds__(256) void k_scale_p(
    const float4* __restrict__ P4, const float4* __restrict__ dv4,
    uint2* __restrict__ WB) {
  int t = blockIdx.x * 256 + threadIdx.x;  // 4 elems/thread
  int col4 = t & (IN_F / 4 - 1);
  float4 p = P4[t];
  float4 d = dv4[col4];
  uint2 o;
  o.x = (uint32_t)f2bf(p.x * d.x) | ((uint32_t)f2bf(p.y * d.y) << 16);
  o.y = (uint32_t)f2bf(p.z * d.z) | ((uint32_t)f2bf(p.w * d.w) << 16);
  WB[t] = o;
}

// ---------------- K5: XB = bf16(x) ----------------
__global__ __launch_bounds__(256) void k_cvt_x(
    const float4* __restrict__ X4, uint4* __restrict__ XB) {
  size_t t = (size_t)blockIdx.x * 256 + threadIdx.x;  // 8 elems/thread
  float4 a = X4[2 * t], b = X4[2 * t + 1];
  uint4 o;
  o.x = (uint32_t)f2bf(a.x) | ((uint32_t)f2bf(a.y) << 16);
  o.y = (uint32_t)f2bf(a.z) | ((uint32_t)f2bf(a.w) << 16);
  o.z = (uint32_t)f2bf(b.x) | ((uint32_t)f2bf(b.y) << 16);
  o.w = (uint32_t)f2bf(b.z) | ((uint32_t)f2bf(b.w) << 16);
  XB[t] = o;
}

// ---------------- K6: C = A*B^T + bias (m97 structure) ----------------
__global__ __launch_bounds__(256) void k_gemm_nt(
    const uint16_t* __restrict__ A,   // [BATCH][IN_F] bf16
    const uint16_t* __restrict__ B,   // [OUT_F][IN_F] bf16
    const float* __restrict__ bias,
    float* __restrict__ C) {
  __shared__ __align__(16) uint16_t lA[128 * 32];
  __shared__ __align__(16) uint16_t lB[128 * 32];

  const int tid = threadIdx.x;
  const int wave = tid >> 6, lane = tid & 63;
  const int bm = blockIdx.x * 128;  // batch tile
  const int bn = blockIdx.y * 128;  // out-feature tile
  const int wm = (wave >> 1) * 64, wn = (wave & 1) * 64;

  floatx4 z = {0.f, 0.f, 0.f, 0.f};
  floatx4 acc[4][4];
#pragma unroll
  for (int i = 0; i < 4; i++)
#pragma unroll
    for (int j = 0; j < 4; j++) acc[i][j] = z;

  const int srow = wave * 32 + (lane >> 2);
  const int scol = (lane & 3) * 8;
  const uint16_t* gA0 = A + (size_t)(bm + srow) * IN_F + scol;
  const uint16_t* gA1 = gA0 + 16 * IN_F;
  const uint16_t* gB0 = B + (size_t)(bn + srow) * IN_F + scol;
  const uint16_t* gB1 = gB0 + 16 * IN_F;
  uint16_t* lA0 = &lA[wave * 1024]; uint16_t* lA1 = lA0 + 512;
  uint16_t* lB0 = &lB[wave * 1024]; uint16_t* lB1 = lB0 + 512;

  const int la = (wm + (lane & 15)) * 32 + (lane >> 4) * 8;
  const int lb = (wn + (lane & 15)) * 32 + (lane >> 4) * 8;

  for (int k0 = 0; k0 < IN_F; k0 += 32) {
    GLD16(gA0, lA0); GLD16(gA1, lA1);
    GLD16(gB0, lB0); GLD16(gB1, lB1);
    gA0 += 32; gA1 += 32; gB0 += 32; gB1 += 32;
    __syncthreads();
    short8 af[4], bf[4];
#pragma unroll
    for (int i = 0; i < 4; i++) {
      af[i] = *(const short8*)&lA[la + i * 512];
      bf[i] = *(const short8*)&lB[lb + i * 512];
    }
#pragma unroll
    for (int i = 0; i < 4; i++)
#pragma unroll
      for (int j = 0; j < 4; j++)
        acc[i][j] = __builtin_amdgcn_mfma_f32_16x16x32_bf16(af[i], bf[j], acc[i][j], 0, 0, 0);
    __syncthreads();
  }

  // C/D layout: col = lane&15, row = (lane>>4)*4 + r  (m89-verified)
#pragma unroll
  for (int j = 0; j < 4; j++) {
    const int col = bn + wn + j * 16 + (lane & 15);
    const float bv = bias[col];
#pragma unroll
    for (int i = 0; i < 4; i++) {
      const int row0 = bm + wm + i * 16 + (lane >> 4) * 4;
#pragma unroll
      for (int r = 0; r < 4; r++)
        C[(size_t)(row0 + r) * OUT_F + col] = acc[i][j][r] + bv;
    }
  }
}

// ================= fp32 fallback (only if ws too small) =================
__global__ __launch_bounds__(256) void fb_gram(const float* __restrict__ P,
                                               float* __restrict__ colsum) {
  __shared__ float red[256];
  const int j = blockIdx.x;
  float s = 0.f;
  for (int i = threadIdx.x; i < IN_F; i += 256) {
    float dot = 0.f;
    for (int k = 0; k < OUT_F; k++)
      dot = fmaf(P[(size_t)k * IN_F + i], P[(size_t)k * IN_F + j], dot);
    s += fabsf(dot);
  }
  red[threadIdx.x] = s;
  __syncthreads();
  for (int st = 128; st > 0; st >>= 1) {
    if (threadIdx.x < st) red[threadIdx.x] += red[threadIdx.x + st];
    __syncthreads();
  }
  if (threadIdx.x == 0) colsum[j] = red[0];
}

__global__ __launch_bounds__(256) void fb_gemm(
    const float* __restrict__ X, const float* __restrict__ P,
    const float* __restrict__ dv, const float* __restrict__ bias,
    float* __restrict__ out) {
  __shared__ __align__(16) float xs[64][20];
  __shared__ __align__(16) float ps[64][20];
  const int bm = blockIdx.x * 64, bn = blockIdx.y * 64;
  const int tx = threadIdx.x & 15, ty = threadIdx.x >> 4;
  float acc[4][4] = {};
  const int r = threadIdx.x >> 2, kc = (threadIdx.x & 3) * 4;
  for (int k0 = 0; k0 < IN_F; k0 += 16) {
    float4 xv = *(const float4*)&X[(size_t)(bm + r) * IN_F + k0 + kc];
    float4 pv = *(const float4*)&P[(size_t)(bn + r) * IN_F + k0 + kc];
    float4 dd = *(const float4*)&dv[k0 + kc];
    float4 pw; pw.x = pv.x * dd.x; pw.y = pv.y * dd.y; pw.z = pv.z * dd.z; pw.w = pv.w * dd.w;
    *(float4*)&xs[r][kc] = xv;
    *(float4*)&ps[r][kc] = pw;
    __syncthreads();
#pragma unroll
    for (int kk = 0; kk < 16; kk++) {
      float a0[4], b0[4];
#pragma unroll
      for (int i = 0; i < 4; i++) a0[i] = xs[ty * 4 + i][kk];
#pragma unroll
      for (int jj = 0; jj < 4; jj++) b0[jj] = ps[tx * 4 + jj][kk];
#pragma unroll
      for (int i = 0; i < 4; i++)
#pragma unroll
        for (int jj = 0; jj < 4; jj++) acc[i][jj] = fmaf(a0[i], b0[jj], acc[i][jj]);
    }
    __syncthreads();
  }
#pragma unroll
  for (int i = 0; i < 4; i++)
#pragma unroll
    for (int jj = 0; jj < 4; jj++) {
      int row = bm + ty * 4 + i, col = bn + tx * 4 + jj;
      out[(size_t)row * OUT_F + col] = acc[i][jj] + bias[col];
    }
}

extern "C" void kernel_launch(void* const* d_in, const int* in_sizes, int n_in,
                              void* d_out, int out_size, void* d_ws, size_t ws_size,
                              hipStream_t stream) {
  const float* x    = (const float*)d_in[0];
  const float* P    = (const float*)d_in[1];
  const float* bias = (const float*)d_in[2];
  float* out = (float*)d_out;
  char* ws = (char*)d_ws;

  const size_t SZ_PT = (size_t)IN_F * OUT_F * 2;   // 8 MB
  const size_t SZ_WB = (size_t)IN_F * OUT_F * 2;   // 8 MB
  const size_t SZ_XB = (size_t)BATCH * IN_F * 2;   // 128 MB
  const size_t need  = SZ_PT + SZ_WB + SZ_XB + 2 * IN_F * sizeof(float) + 256;

  if (ws_size >= need) {
    uint16_t* PT = (uint16_t*)ws;
    uint16_t* WB = (uint16_t*)(ws + SZ_PT);
    uint16_t* XB = (uint16_t*)(ws + SZ_PT + SZ_WB);
    float* colsum = (float*)(ws + SZ_PT + SZ_WB + SZ_XB);
    float* dv = colsum + IN_F;

    hipMemsetAsync(colsum, 0, IN_F * sizeof(float), stream);
    k_transpose_bf16<<<dim3(64, 64), 256, 0, stream>>>(P, PT);
    k_gram_colsum<<<dim3(16, 16), 256, 0, stream>>>(PT, colsum);
    k_finalize_d<<<8, 256, 0, stream>>>(colsum, dv);
    k_scale_p<<<(IN_F * OUT_F / 4) / 256, 256, 0, stream>>>(
        (const float4*)P, (const float4*)dv, (uint2*)WB);
    k_cvt_x<<<(int)(((size_t)BATCH * IN_F / 8) / 256), 256, 0, stream>>>(
        (const float4*)x, (uint4*)XB);
    k_gemm_nt<<<dim3(BATCH / 128, OUT_F / 128), 256, 0, stream>>>(XB, WB, bias, out);
  } else {
    float* colsum = (float*)ws;
    float* dv = colsum + IN_F;
    fb_gram<<<IN_F, 256, 0, stream>>>(P, colsum);
    k_finalize_d<<<8, 256, 0, stream>>>(colsum, dv);
    fb_gemm<<<dim3(BATCH / 64, OUT_F / 64), 256, 0, stream>>>(x, P, dv, bias, out);
  }
}

// Round 2
// 878.744 us; speedup vs baseline: 1.0954x; 1.0954x over previous
//
#include <hip/hip_runtime.h>
#include <hip/hip_bf16.h>
#include <stdint.h>

#define IN_F  2048
#define OUT_F 2048
#define BATCH 32768

typedef __attribute__((ext_vector_type(8))) short  short8;   // 8 x bf16 (4 VGPRs)
typedef __attribute__((ext_vector_type(4))) float  floatx4;  // MFMA C/D

static constexpr int LDT = 40;  // ushorts per LDS row: 32 data + 8 pad (2-way banks, free)

__device__ __forceinline__ uint16_t f2bf(float f) {
  union { float f; uint32_t u; } v; v.f = f;
  uint32_t r = v.u + 0x7FFFu + ((v.u >> 16) & 1u);  // RNE
  return (uint16_t)(r >> 16);
}

// Register-staged double-buffered 128x128 K-loop (NT, bf16, 16x16x32 MFMA).
// Loads for tile k+1 issue at top of iter k (plain global_load -> VGPR),
// MFMAs consume LDS buf p, ds_write_b128 stages regs into buf 1-p (vmcnt
// wait lands here, one compute-section after issue), one barrier per iter.
__device__ __forceinline__ void gemm128_pipeline(
    const uint16_t* __restrict__ A, const uint16_t* __restrict__ B,
    int bm, int bn, int K, uint16_t* sA, uint16_t* sB,
    floatx4 (&acc)[4][4]) {
  const int tid  = threadIdx.x;
  const int wave = tid >> 6, lane = tid & 63;
  const int wm = (wave >> 1) * 64, wn = (wave & 1) * 64;

  const int srow = wave * 32 + (lane >> 2);   // staging row 0..127
  const int scol = (lane & 3) * 8;            // ushort offset within row
  const uint16_t* gA = A + (size_t)(bm + srow) * K + scol;
  const uint16_t* gB = B + (size_t)(bn + srow) * K + scol;

  const int wAo  = srow * LDT + scol;
  const int wAo2 = (srow + 16) * LDT + scol;

  const int ra = (wm + (lane & 15)) * LDT + (lane >> 4) * 8;
  const int rb = (wn + (lane & 15)) * LDT + (lane >> 4) * 8;

  // prologue: tile 0 -> regs -> LDS buf 0
  short8 rA0 = *(const short8*)gA;
  short8 rA1 = *(const short8*)(gA + 16 * (size_t)K);
  short8 rB0 = *(const short8*)gB;
  short8 rB1 = *(const short8*)(gB + 16 * (size_t)K);
  gA += 32; gB += 32;
  *(short8*)&sA[wAo]  = rA0;  *(short8*)&sA[wAo2] = rA1;
  *(short8*)&sB[wAo]  = rB0;  *(short8*)&sB[wAo2] = rB1;
  __syncthreads();

  const int NK = K / 32;
  int p = 0;
  for (int k = 0; k < NK; k++, p ^= 1) {
    if (k + 1 < NK) {  // prefetch next tile into regs
      rA0 = *(const short8*)gA;
      rA1 = *(const short8*)(gA + 16 * (size_t)K);
      rB0 = *(const short8*)gB;
      rB1 = *(const short8*)(gB + 16 * (size_t)K);
      gA += 32; gB += 32;
    }
    const uint16_t* cA = sA + p * (128 * LDT);
    const uint16_t* cB = sB + p * (128 * LDT);
    short8 af[4], bf[4];
#pragma unroll
    for (int i = 0; i < 4; i++) {
      af[i] = *(const short8*)&cA[ra + i * 16 * LDT];
      bf[i] = *(const short8*)&cB[rb + i * 16 * LDT];
    }
#pragma unroll
    for (int i = 0; i < 4; i++)
#pragma unroll
      for (int j = 0; j < 4; j++)
        acc[i][j] = __builtin_amdgcn_mfma_f32_16x16x32_bf16(af[i], bf[j], acc[i][j], 0, 0, 0);
    if (k + 1 < NK) {  // stage prefetched regs into the other buffer
      uint16_t* dA = sA + (p ^ 1) * (128 * LDT);
      uint16_t* dB = sB + (p ^ 1) * (128 * LDT);
      *(short8*)&dA[wAo]  = rA0;  *(short8*)&dA[wAo2] = rA1;
      *(short8*)&dB[wAo]  = rB0;  *(short8*)&dB[wAo2] = rB1;
    }
    __syncthreads();
  }
}

// ---------------- K1: P -> PT (bf16 transposed) and PB (bf16 straight) ----------------
__global__ __launch_bounds__(256) void k_prep(
    const float* __restrict__ P, uint16_t* __restrict__ PT,
    uint16_t* __restrict__ PB) {
  __shared__ float tile[32][33];
  const int bx = blockIdx.x * 32;  // i (IN)
  const int by = blockIdx.y * 32;  // k (OUT)
  const int tx = threadIdx.x & 31;
  const int ty = threadIdx.x >> 5;  // 0..7
#pragma unroll
  for (int i = 0; i < 32; i += 8) {
    float v = P[(size_t)(by + ty + i) * IN_F + bx + tx];
    tile[ty + i][tx] = v;
    PB[(size_t)(by + ty + i) * IN_F + bx + tx] = f2bf(v);
  }
  __syncthreads();
#pragma unroll
  for (int i = 0; i < 32; i += 8)
    PT[(size_t)(bx + ty + i) * IN_F + by + tx] = f2bf(tile[tx][ty + i]);
}

// ------- K2: colsum[j] += sum_i |sum_k PT[i,k] PT[j,k]| -------
__global__ __launch_bounds__(256) void k_gram_colsum(
    const uint16_t* __restrict__ PT, float* __restrict__ colsum) {
  __shared__ __align__(16) uint16_t sA[2 * 128 * LDT];
  __shared__ __align__(16) uint16_t sB[2 * 128 * LDT];
  __shared__ float colpart[128];

  const int tid = threadIdx.x;
  const int wave = tid >> 6, lane = tid & 63;
  const int bm = blockIdx.x * 128, bn = blockIdx.y * 128;
  const int wn = (wave & 1) * 64;

  floatx4 z = {0.f, 0.f, 0.f, 0.f};
  floatx4 acc[4][4];
#pragma unroll
  for (int i = 0; i < 4; i++)
#pragma unroll
    for (int j = 0; j < 4; j++) acc[i][j] = z;

  gemm128_pipeline(PT, PT, bm, bn, OUT_F, sA, sB, acc);

  if (tid < 128) colpart[tid] = 0.f;
  __syncthreads();
#pragma unroll
  for (int j = 0; j < 4; j++) {
    float s = 0.f;
#pragma unroll
    for (int i = 0; i < 4; i++)
#pragma unroll
      for (int r = 0; r < 4; r++) s += fabsf(acc[i][j][r]);
    atomicAdd(&colpart[wn + j * 16 + (lane & 15)], s);
  }
  __syncthreads();
  if (tid < 128) atomicAdd(&colsum[bn + tid], colpart[tid]);
}

// ---------------- K3 ----------------
__global__ void k_finalize_d(const float* __restrict__ colsum, float* __restrict__ dv) {
  int i = blockIdx.x * blockDim.x + threadIdx.x;
  if (i < IN_F) dv[i] = 1.0f / sqrtf(colsum[i] + 1e-10f);
}

// ---------------- K4: XB = bf16(x * d)  (d folded into x, not P) ----------------
__global__ __launch_bounds__(256) void k_cvt_x(
    const float4* __restrict__ X4, const float4* __restrict__ dv4,
    uint4* __restrict__ XB) {
  size_t t = (size_t)blockIdx.x * 256 + threadIdx.x;  // 8 elems/thread
  int c4 = (int)((2 * t) & (IN_F / 4 - 1));
  float4 a = X4[2 * t], b = X4[2 * t + 1];
  float4 d0 = dv4[c4], d1 = dv4[c4 + 1];
  uint4 o;
  o.x = (uint32_t)f2bf(a.x * d0.x) | ((uint32_t)f2bf(a.y * d0.y) << 16);
  o.y = (uint32_t)f2bf(a.z * d0.z) | ((uint32_t)f2bf(a.w * d0.w) << 16);
  o.z = (uint32_t)f2bf(b.x * d1.x) | ((uint32_t)f2bf(b.y * d1.y) << 16);
  o.w = (uint32_t)f2bf(b.z * d1.z) | ((uint32_t)f2bf(b.w * d1.w) << 16);
  XB[t] = o;
}

// ---------------- K5: out = XB * PB^T + bias ----------------
__global__ __launch_bounds__(256) void k_gemm_nt(
    const uint16_t* __restrict__ A,   // [BATCH][IN_F] bf16 (x*d)
    const uint16_t* __restrict__ B,   // [OUT_F][IN_F] bf16 (P)
    const float* __restrict__ bias,
    float* __restrict__ C) {
  __shared__ __align__(16) uint16_t sA[2 * 128 * LDT];
  __shared__ __align__(16) uint16_t sB[2 * 128 * LDT];

  const int tid = threadIdx.x;
  const int wave = tid >> 6, lane = tid & 63;
  const int bm = blockIdx.x * 128;  // batch tile
  const int bn = blockIdx.y * 128;  // out-feature tile
  const int wm = (wave >> 1) * 64, wn = (wave & 1) * 64;

  floatx4 z = {0.f, 0.f, 0.f, 0.f};
  floatx4 acc[4][4];
#pragma unroll
  for (int i = 0; i < 4; i++)
#pragma unroll
    for (int j = 0; j < 4; j++) acc[i][j] = z;

  gemm128_pipeline(A, B, bm, bn, IN_F, sA, sB, acc);

  // C/D layout: col = lane&15, row = (lane>>4)*4 + r  (m89-verified)
#pragma unroll
  for (int j = 0; j < 4; j++) {
    const int col = bn + wn + j * 16 + (lane & 15);
    const float bv = bias[col];
#pragma unroll
    for (int i = 0; i < 4; i++) {
      const int row0 = bm + wm + i * 16 + (lane >> 4) * 4;
#pragma unroll
      for (int r = 0; r < 4; r++)
        C[(size_t)(row0 + r) * OUT_F + col] = acc[i][j][r] + bv;
    }
  }
}

// ================= fp32 fallback (only if ws too small) =================
__global__ __launch_bounds__(256) void fb_gram(const float* __restrict__ P,
                                               float* __restrict__ colsum) {
  __shared__ float red[256];
  const int j = blockIdx.x;
  float s = 0.f;
  for (int i = threadIdx.x; i < IN_F; i += 256) {
    float dot = 0.f;
    for (int k = 0; k < OUT_F; k++)
      dot = fmaf(P[(size_t)k * IN_F + i], P[(size_t)k * IN_F + j], dot);
    s += fabsf(dot);
  }
  red[threadIdx.x] = s;
  __syncthreads();
  for (int st = 128; st > 0; st >>= 1) {
    if (threadIdx.x < st) red[threadIdx.x] += red[threadIdx.x + st];
    __syncthreads();
  }
  if (threadIdx.x == 0) colsum[j] = red[0];
}

__global__ __launch_bounds__(256) void fb_gemm(
    const float* __restrict__ X, const float* __restrict__ P,
    const float* __restrict__ dv, const float* __restrict__ bias,
    float* __restrict__ out) {
  __shared__ __align__(16) float xs[64][20];
  __shared__ __align__(16) float ps[64][20];
  const int bm = blockIdx.x * 64, bn = blockIdx.y * 64;
  const int tx = threadIdx.x & 15, ty = threadIdx.x >> 4;
  float acc[4][4] = {};
  const int r = threadIdx.x >> 2, kc = (threadIdx.x & 3) * 4;
  for (int k0 = 0; k0 < IN_F; k0 += 16) {
    float4 xv = *(const float4*)&X[(size_t)(bm + r) * IN_F + k0 + kc];
    float4 pv = *(const float4*)&P[(size_t)(bn + r) * IN_F + k0 + kc];
    float4 dd = *(const float4*)&dv[k0 + kc];
    float4 pw; pw.x = pv.x * dd.x; pw.y = pv.y * dd.y; pw.z = pv.z * dd.z; pw.w = pv.w * dd.w;
    *(float4*)&xs[r][kc] = xv;
    *(float4*)&ps[r][kc] = pw;
    __syncthreads();
#pragma unroll
    for (int kk = 0; kk < 16; kk++) {
      float a0[4], b0[4];
#pragma unroll
      for (int i = 0; i < 4; i++) a0[i] = xs[ty * 4 + i][kk];
#pragma unroll
      for (int jj = 0; jj < 4; jj++) b0[jj] = ps[tx * 4 + jj][kk];
#pragma unroll
      for (int i = 0; i < 4; i++)
#pragma unroll
        for (int jj = 0; jj < 4; jj++) acc[i][jj] = fmaf(a0[i], b0[jj], acc[i][jj]);
    }
    __syncthreads();
  }
#pragma unroll
  for (int i = 0; i < 4; i++)
#pragma unroll
    for (int jj = 0; jj < 4; jj++) {
      int row = bm + ty * 4 + i, col = bn + tx * 4 + jj;
      out[(size_t)row * OUT_F + col] = acc[i][jj] + bias[col];
    }
}

extern "C" void kernel_launch(void* const* d_in, const int* in_sizes, int n_in,
                              void* d_out, int out_size, void* d_ws, size_t ws_size,
                              hipStream_t stream) {
  const float* x    = (const float*)d_in[0];
  const float* P    = (const float*)d_in[1];
  const float* bias = (const float*)d_in[2];
  float* out = (float*)d_out;
  char* ws = (char*)d_ws;

  const size_t SZ_PT = (size_t)IN_F * OUT_F * 2;   // 8 MB
  const size_t SZ_PB = (size_t)IN_F * OUT_F * 2;   // 8 MB
  const size_t SZ_XB = (size_t)BATCH * IN_F * 2;   // 128 MB
  const size_t need  = SZ_PT + SZ_PB + SZ_XB + 2 * IN_F * sizeof(float) + 256;

  if (ws_size >= need) {
    uint16_t* PT = (uint16_t*)ws;
    uint16_t* PB = (uint16_t*)(ws + SZ_PT);
    uint16_t* XB = (uint16_t*)(ws + SZ_PT + SZ_PB);
    float* colsum = (float*)(ws + SZ_PT + SZ_PB + SZ_XB);
    float* dv = colsum + IN_F;

    hipMemsetAsync(colsum, 0, IN_F * sizeof(float), stream);
    k_prep<<<dim3(64, 64), 256, 0, stream>>>(P, PT, PB);
    k_gram_colsum<<<dim3(16, 16), 256, 0, stream>>>(PT, colsum);
    k_finalize_d<<<8, 256, 0, stream>>>(colsum, dv);
    k_cvt_x<<<(int)(((size_t)BATCH * IN_F / 8) / 256), 256, 0, stream>>>(
        (const float4*)x, (const float4*)dv, (uint4*)XB);
    k_gemm_nt<<<dim3(BATCH / 128, OUT_F / 128), 256, 0, stream>>>(XB, PB, bias, out);
  } else {
    float* colsum = (float*)ws;
    float* dv = colsum + IN_F;
    fb_gram<<<IN_F, 256, 0, stream>>>(P, colsum);
    k_finalize_d<<<8, 256, 0, stream>>>(colsum, dv);
    fb_gemm<<<dim3(BATCH / 64, OUT_F / 64), 256, 0, stream>>>(x, P, dv, bias, out);
  }
}